// Round 3
// baseline (920.111 us; speedup 1.0000x reference)
//
#include <hip/hip_runtime.h>
#include <cstddef>

// DynamicRouting: B=32, C1=4096, C2=32, D2=16, 3 routing iterations.
// digit_caps_stopped == digit_caps (bit-identical) -> read d_in[0] only.
//
// iter0: w = 1/32 uniform            -> v0 = squash(colsum(x)/32 + bias)
// iter1: w1 = softmax_c2(x.v0)       -> v1 = squash(sum_c1 w1*x + bias)
// iter2: w2 = softmax_c2(x.(v0+v1))  -> out = squash(sum_c1 w2*x + bias)
//
// Pass 0 streams fp32 x once (nontemporal), writes a bf16 copy (xb) to ws;
// passes 1/2 read xb (half the bytes, L3-resident candidate). Each pass's
// squash is fused via last-block-per-b fold (device-scope atomic counter).

namespace {
typedef float  v2f __attribute__((ext_vector_type(2)));
typedef float  v4f __attribute__((ext_vector_type(4)));
typedef unsigned int v4u __attribute__((ext_vector_type(4)));

constexpr int B_  = 32;
constexpr int C1_ = 4096;
constexpr int C2_ = 32;
constexpr int D2_ = 16;
constexpr int ROW_ = C2_ * D2_;   // 512 elems per (b,c1)
constexpr int BPB  = 64;          // partial blocks per batch element
constexpr int C1B  = C1_ / BPB;   // 64 rows per block

__device__ inline void pk_fma(v2f& c, v2f a, v2f b) {
  asm("v_pk_fma_f32 %0, %1, %2, %0" : "+v"(c) : "v"(a), "v"(b));
}
__device__ inline void pk_add(v2f& c, v2f a) {
  asm("v_pk_add_f32 %0, %1, %0" : "+v"(c) : "v"(a));
}
__device__ inline float asf(unsigned u) { union { unsigned u; float f; } c; c.u = u; return c.f; }
__device__ inline unsigned asu(float f) { union { float f; unsigned u; } c; c.f = f; return c.u; }
__device__ inline unsigned bf16rne(float f) {  // round-to-nearest-even bf16 bits
  unsigned u = asu(f);
  return (u + 0x7fffu + ((u >> 16) & 1u)) >> 16;
}

// Block tail: wave-pair reduce -> LDS reduce -> P write -> last-block-of-b
// folds 64 partials, adds bias, squashes over D2, writes vout[b].
__device__ inline void reduce_store_fold(
    float (*red)[ROW_], float* af /*16 floats (v4f-aligned)*/,
    float* __restrict__ P, const float* __restrict__ bias,
    float* __restrict__ vout, unsigned* __restrict__ cnt,
    float scale, int b, int blk, int tid, int c2) {
#pragma unroll
  for (int k = 0; k < 16; ++k) af[k] += __shfl_xor(af[k], 32);
  const int wave = tid >> 6, lane = tid & 63;
  if (lane < 32) {
    v4f* dst = reinterpret_cast<v4f*>(&red[wave][c2 * D2_]);
    const v4f* s4 = reinterpret_cast<const v4f*>(af);
#pragma unroll
    for (int k = 0; k < 4; ++k) { const int jj = (k + c2) & 3; dst[jj] = s4[jj]; }
  }
  __syncthreads();
  if (tid < ROW_ / 4) {
    v4f s = {0.f, 0.f, 0.f, 0.f};
#pragma unroll
    for (int w = 0; w < 4; ++w) s += reinterpret_cast<const v4f*>(red[w])[tid];
    reinterpret_cast<v4f*>(P + ((size_t)b * BPB + blk) * ROW_)[tid] = s;
  }
  __threadfence();          // release this block's P slice (device scope)
  __syncthreads();
  __shared__ int winner;
  if (tid == 0) winner = (atomicAdd(&cnt[b], 1u) == (unsigned)(BPB - 1)) ? 1 : 0;
  __syncthreads();
  if (!winner) return;
  if (tid < 128) {
    __threadfence();        // acquire: see all 64 blocks' P slices
    const int cc = tid >> 2, q = tid & 3;
    const float* pb = P + (size_t)b * BPB * ROW_ + cc * D2_ + q * 4;
    v4f s = {0.f, 0.f, 0.f, 0.f};
#pragma unroll 8
    for (int k = 0; k < BPB; ++k)
      s += *reinterpret_cast<const v4f*>(pb + (size_t)k * ROW_);
    const v4f bj = *reinterpret_cast<const v4f*>(bias + cc * D2_ + q * 4);
    v4f t = s * scale + bj;
    float sq = t.x * t.x + t.y * t.y + t.z * t.z + t.w * t.w;
    sq += __shfl_xor(sq, 1, 4);
    sq += __shfl_xor(sq, 2, 4);
    const float f = sq / ((1.f + sq) * sqrtf(sq + 1e-8f));
    *reinterpret_cast<v4f*>(vout + (size_t)b * ROW_ + cc * D2_ + q * 4) = t * f;
  }
}

// Pass 0: colsum of fp32 x (nontemporal reads) + write bf16 copy xb.
__global__ __launch_bounds__(256) void pass0(
    const float* __restrict__ x, unsigned short* __restrict__ xb,
    const float* __restrict__ bias, float* __restrict__ P,
    float* __restrict__ v0, unsigned* __restrict__ cnt) {
  const int tid = threadIdx.x;
  const int c2 = tid & 31, rs = tid >> 5;
  const int b = blockIdx.x / BPB, blk = blockIdx.x % BPB;

  v4f acc4[4];
#pragma unroll
  for (int j = 0; j < 4; ++j) acc4[j] = (v4f){0.f, 0.f, 0.f, 0.f};
  v2f* acc = reinterpret_cast<v2f*>(acc4);

  const size_t off = ((size_t)b * C1_ + (size_t)blk * C1B) * ROW_ + (size_t)c2 * D2_;
#pragma unroll 2
  for (int r = rs; r < C1B; r += 8) {
    const v4f* xp = reinterpret_cast<const v4f*>(x + off + (size_t)r * ROW_);
    v4f x4[4];
#pragma unroll
    for (int j = 0; j < 4; ++j) x4[j] = __builtin_nontemporal_load(xp + j);
    v2f* x2 = reinterpret_cast<v2f*>(x4);
#pragma unroll
    for (int j = 0; j < 8; ++j) pk_add(acc[j], x2[j]);
    // convert 16 floats -> 16 bf16 (RNE), pack into 2x uint4, store
    const float* xf = reinterpret_cast<const float*>(x4);
    unsigned hw[8];
#pragma unroll
    for (int i = 0; i < 8; ++i)
      hw[i] = bf16rne(xf[2 * i]) | (bf16rne(xf[2 * i + 1]) << 16);
    v4u* hp = reinterpret_cast<v4u*>(xb + off + (size_t)r * ROW_);
    hp[0] = (v4u){hw[0], hw[1], hw[2], hw[3]};
    hp[1] = (v4u){hw[4], hw[5], hw[6], hw[7]};
  }

  __shared__ float red[4][ROW_];
  reduce_store_fold(red, reinterpret_cast<float*>(acc4), P, bias, v0, cnt,
                    1.0f / C2_, b, blk, tid, c2);
}

// Passes 1/2: read bf16 xb, logits vs va (v0 or v0+v1), softmax over c2,
// weighted accumulate.
template <int PHASE>
__global__ __launch_bounds__(256) void passN(
    const unsigned short* __restrict__ xb, const float* __restrict__ v0,
    const float* __restrict__ v1, const float* __restrict__ bias,
    float* __restrict__ P, float* __restrict__ vout, unsigned* __restrict__ cnt) {
  const int tid = threadIdx.x;
  const int c2 = tid & 31, rs = tid >> 5;
  const int b = blockIdx.x / BPB, blk = blockIdx.x % BPB;

  v2f va[8];
  {
    const v2f* vp = reinterpret_cast<const v2f*>(v0 + (size_t)b * ROW_ + c2 * D2_);
#pragma unroll
    for (int j = 0; j < 8; ++j) va[j] = vp[j];
    if (PHASE == 2) {
      const v2f* wp = reinterpret_cast<const v2f*>(v1 + (size_t)b * ROW_ + c2 * D2_);
#pragma unroll
      for (int j = 0; j < 8; ++j) va[j] += wp[j];
    }
  }

  v4f acc4[4];
#pragma unroll
  for (int j = 0; j < 4; ++j) acc4[j] = (v4f){0.f, 0.f, 0.f, 0.f};
  v2f* acc = reinterpret_cast<v2f*>(acc4);

  const size_t off = ((size_t)b * C1_ + (size_t)blk * C1B) * ROW_ + (size_t)c2 * D2_;
#pragma unroll 2
  for (int r = rs; r < C1B; r += 8) {
    const v4u* hp = reinterpret_cast<const v4u*>(xb + off + (size_t)r * ROW_);
    const v4u u0 = hp[0], u1 = hp[1];
    const unsigned u[8] = {u0.x, u0.y, u0.z, u0.w, u1.x, u1.y, u1.z, u1.w};
    v2f xv[8];
#pragma unroll
    for (int i = 0; i < 8; ++i) {
      xv[i].x = asf(u[i] << 16);
      xv[i].y = asf(u[i] & 0xffff0000u);
    }
    v2f dp = {0.f, 0.f};
#pragma unroll
    for (int i = 0; i < 8; ++i) pk_fma(dp, xv[i], va[i]);
    const float a = dp.x + dp.y;  // |a| <~ 15 -> exp safe without max-shift
    const float e = __expf(a);
    float s = e;
#pragma unroll
    for (int o = 16; o; o >>= 1) s += __shfl_xor(s, o, 32);
    const float w = e * __builtin_amdgcn_rcpf(s);
    const v2f w2 = {w, w};
#pragma unroll
    for (int i = 0; i < 8; ++i) pk_fma(acc[i], xv[i], w2);
  }

  __shared__ float red[4][ROW_];
  reduce_store_fold(red, reinterpret_cast<float*>(acc4), P, bias, vout, cnt,
                    1.0f, b, blk, tid, c2);
}

// ---------- fp32 fallback (R2 path) if workspace is too small ----------
__global__ __launch_bounds__(256) void fb_pass(
    const float* __restrict__ x, const float* __restrict__ v0,
    const float* __restrict__ v1, const float* __restrict__ bias,
    float* __restrict__ P, float* __restrict__ vout, unsigned* __restrict__ cnt,
    float scale, int phase) {
  const int tid = threadIdx.x;
  const int c2 = tid & 31, rs = tid >> 5;
  const int b = blockIdx.x / BPB, blk = blockIdx.x % BPB;
  v2f va[8];
  if (phase >= 1) {
    const v2f* vp = reinterpret_cast<const v2f*>(v0 + (size_t)b * ROW_ + c2 * D2_);
#pragma unroll
    for (int j = 0; j < 8; ++j) va[j] = vp[j];
    if (phase == 2) {
      const v2f* wp = reinterpret_cast<const v2f*>(v1 + (size_t)b * ROW_ + c2 * D2_);
#pragma unroll
      for (int j = 0; j < 8; ++j) va[j] += wp[j];
    }
  }
  v4f acc4[4];
#pragma unroll
  for (int j = 0; j < 4; ++j) acc4[j] = (v4f){0.f, 0.f, 0.f, 0.f};
  v2f* acc = reinterpret_cast<v2f*>(acc4);
  const size_t off = ((size_t)b * C1_ + (size_t)blk * C1B) * ROW_ + (size_t)c2 * D2_;
  for (int r = rs; r < C1B; r += 8) {
    const v4f* xp = reinterpret_cast<const v4f*>(x + off + (size_t)r * ROW_);
    v4f x4[4];
#pragma unroll
    for (int j = 0; j < 4; ++j) x4[j] = xp[j];
    v2f* x2 = reinterpret_cast<v2f*>(x4);
    float w = 1.0f;
    if (phase >= 1) {
      v2f dp = {0.f, 0.f};
#pragma unroll
      for (int j = 0; j < 8; ++j) pk_fma(dp, x2[j], va[j]);
      const float a = dp.x + dp.y;
      const float e = __expf(a);
      float s = e;
#pragma unroll
      for (int o = 16; o; o >>= 1) s += __shfl_xor(s, o, 32);
      w = e * __builtin_amdgcn_rcpf(s);
    }
    const v2f w2 = {w, w};
#pragma unroll
    for (int j = 0; j < 8; ++j) pk_fma(acc[j], x2[j], w2);
  }
  __shared__ float red[4][ROW_];
  reduce_store_fold(red, reinterpret_cast<float*>(acc4), P, bias, vout, cnt,
                    scale, b, blk, tid, c2);
}

}  // namespace

extern "C" void kernel_launch(void* const* d_in, const int* in_sizes, int n_in,
                              void* d_out, int out_size, void* d_ws, size_t ws_size,
                              hipStream_t stream) {
  const float* x    = reinterpret_cast<const float*>(d_in[0]);  // digit_caps
  const float* bias = reinterpret_cast<const float*>(d_in[2]);
  float* out = reinterpret_cast<float*>(d_out);

  const size_t xb_elems = (size_t)B_ * C1_ * ROW_;        // 64 Mi bf16 = 128 MiB
  const size_t P_elems  = (size_t)B_ * BPB * ROW_;        // 4 MiB fp32
  const size_t v_elems  = (size_t)B_ * ROW_;              // 64 KiB fp32
  const size_t need = xb_elems * 2 + (P_elems + 2 * v_elems) * 4 + 96 * 4;

  const dim3 grid(B_ * BPB);
  const dim3 blk(256);

  if (ws_size >= need) {
    unsigned short* xb = reinterpret_cast<unsigned short*>(d_ws);
    float* P  = reinterpret_cast<float*>(xb + xb_elems);
    float* v0 = P + P_elems;
    float* v1 = v0 + v_elems;
    unsigned* cnt = reinterpret_cast<unsigned*>(v1 + v_elems);
    hipMemsetAsync(cnt, 0, 96 * sizeof(unsigned), stream);
    pass0<<<grid, blk, 0, stream>>>(x, xb, bias, P, v0, cnt);
    passN<1><<<grid, blk, 0, stream>>>(xb, v0, nullptr, bias, P, v1, cnt + 32);
    passN<2><<<grid, blk, 0, stream>>>(xb, v0, v1, bias, P, out, cnt + 64);
  } else {
    float* P  = reinterpret_cast<float*>(d_ws);
    float* v0 = P + P_elems;
    float* v1 = v0 + v_elems;
    unsigned* cnt = reinterpret_cast<unsigned*>(v1 + v_elems);
    hipMemsetAsync(cnt, 0, 96 * sizeof(unsigned), stream);
    fb_pass<<<grid, blk, 0, stream>>>(x, nullptr, nullptr, bias, P, v0, cnt, 1.0f / C2_, 0);
    fb_pass<<<grid, blk, 0, stream>>>(x, v0, nullptr, bias, P, v1, cnt + 32, 1.0f, 1);
    fb_pass<<<grid, blk, 0, stream>>>(x, v0, v1, bias, P, out, cnt + 64, 1.0f, 2);
  }
}

// Round 4
// 174.050 us; speedup vs baseline: 5.2865x; 5.2865x over previous
//
#include <hip/hip_runtime.h>
#include <cstddef>

// DynamicRouting: B=32, C1=4096, C2=32, D2=16, 3 routing iterations.
// digit_caps_stopped == digit_caps (bit-identical) -> read d_in[0] only.
//
// iter0: w = 1/32 uniform            -> v0 = squash(colsum(x)/32 + bias)
// iter1: w1 = softmax_c2(x.v0)       -> v1 = squash(sum_c1 w1*x + bias)
// iter2: w2 = softmax_c2(x.(v0+v1))  -> out = squash(sum_c1 w2*x + bias)
//
// R3 lesson: NO __threadfence / atomic fusion -- agent-scope fences flush the
// non-coherent per-XCD L2s (~10x slowdown). Cross-pass visibility comes from
// kernel boundaries. Pass 0 streams fp32 x once (nontemporal) and writes a
// bf16 copy; passes 1/2 read the bf16 copy (half bytes, L3-candidate).

namespace {
typedef float  v2f __attribute__((ext_vector_type(2)));
typedef float  v4f __attribute__((ext_vector_type(4)));
typedef unsigned int v4u __attribute__((ext_vector_type(4)));

constexpr int B_  = 32;
constexpr int C1_ = 4096;
constexpr int C2_ = 32;
constexpr int D2_ = 16;
constexpr int ROW_ = C2_ * D2_;   // 512 elems per (b,c1)
constexpr int BPB  = 64;          // partial blocks per batch element
constexpr int C1B  = C1_ / BPB;   // 64 rows per block

__device__ inline void pk_fma(v2f& c, v2f a, v2f b) {
  asm("v_pk_fma_f32 %0, %1, %2, %0" : "+v"(c) : "v"(a), "v"(b));
}
__device__ inline void pk_add(v2f& c, v2f a) {
  asm("v_pk_add_f32 %0, %1, %0" : "+v"(c) : "v"(a));
}
__device__ inline float asf(unsigned u) { union { unsigned u; float f; } c; c.u = u; return c.f; }
__device__ inline unsigned asu(float f) { union { float f; unsigned u; } c; c.f = f; return c.u; }
__device__ inline unsigned bf16rne(float f) {  // round-to-nearest-even bf16 bits
  unsigned u = asu(f);
  return (u + 0x7fffu + ((u >> 16) & 1u)) >> 16;
}

// Shared block tail: wave-pair reduce -> LDS reduce -> P partial write.
__device__ inline void reduce_store(
    float (*red)[ROW_], float* af /*16 floats (v4f-aligned)*/,
    float* __restrict__ P, int b, int blk, int tid, int c2) {
#pragma unroll
  for (int k = 0; k < 16; ++k) af[k] += __shfl_xor(af[k], 32);
  const int wave = tid >> 6, lane = tid & 63;
  if (lane < 32) {
    v4f* dst = reinterpret_cast<v4f*>(&red[wave][c2 * D2_]);
    const v4f* s4 = reinterpret_cast<const v4f*>(af);
#pragma unroll
    for (int k = 0; k < 4; ++k) { const int jj = (k + c2) & 3; dst[jj] = s4[jj]; }
  }
  __syncthreads();
  if (tid < ROW_ / 4) {
    v4f s = {0.f, 0.f, 0.f, 0.f};
#pragma unroll
    for (int w = 0; w < 4; ++w) s += reinterpret_cast<const v4f*>(red[w])[tid];
    reinterpret_cast<v4f*>(P + ((size_t)b * BPB + blk) * ROW_)[tid] = s;
  }
}

// Pass 0: colsum of fp32 x (nontemporal reads) + write bf16 copy xb.
__global__ __launch_bounds__(256) void pass0(
    const float* __restrict__ x, unsigned short* __restrict__ xb,
    float* __restrict__ P) {
  const int tid = threadIdx.x;
  const int c2 = tid & 31, rs = tid >> 5;
  const int b = blockIdx.x / BPB, blk = blockIdx.x % BPB;

  v4f acc4[4];
#pragma unroll
  for (int j = 0; j < 4; ++j) acc4[j] = (v4f){0.f, 0.f, 0.f, 0.f};
  v2f* acc = reinterpret_cast<v2f*>(acc4);

  const size_t off = ((size_t)b * C1_ + (size_t)blk * C1B) * ROW_ + (size_t)c2 * D2_;
#pragma unroll 2
  for (int r = rs; r < C1B; r += 8) {
    const v4f* xp = reinterpret_cast<const v4f*>(x + off + (size_t)r * ROW_);
    v4f x4[4];
#pragma unroll
    for (int j = 0; j < 4; ++j) x4[j] = __builtin_nontemporal_load(xp + j);
    v2f* x2 = reinterpret_cast<v2f*>(x4);
#pragma unroll
    for (int j = 0; j < 8; ++j) pk_add(acc[j], x2[j]);
    // convert 16 floats -> 16 bf16 (RNE), pack, 2x16B store
    const float* xf = reinterpret_cast<const float*>(x4);
    unsigned hw[8];
#pragma unroll
    for (int i = 0; i < 8; ++i)
      hw[i] = bf16rne(xf[2 * i]) | (bf16rne(xf[2 * i + 1]) << 16);
    v4u* hp = reinterpret_cast<v4u*>(xb + off + (size_t)r * ROW_);
    hp[0] = (v4u){hw[0], hw[1], hw[2], hw[3]};
    hp[1] = (v4u){hw[4], hw[5], hw[6], hw[7]};
  }

  __shared__ float red[4][ROW_];
  reduce_store(red, reinterpret_cast<float*>(acc4), P, b, blk, tid, c2);
}

// Passes 1/2: read bf16 xb, logit vs va (v0 or v0+v1), softmax over c2,
// weighted accumulate.
template <int PHASE>
__global__ __launch_bounds__(256) void passN(
    const unsigned short* __restrict__ xb, const float* __restrict__ v0,
    const float* __restrict__ v1, float* __restrict__ P) {
  const int tid = threadIdx.x;
  const int c2 = tid & 31, rs = tid >> 5;
  const int b = blockIdx.x / BPB, blk = blockIdx.x % BPB;

  v2f va[8];
  {
    const v2f* vp = reinterpret_cast<const v2f*>(v0 + (size_t)b * ROW_ + c2 * D2_);
#pragma unroll
    for (int j = 0; j < 8; ++j) va[j] = vp[j];
    if (PHASE == 2) {
      const v2f* wp = reinterpret_cast<const v2f*>(v1 + (size_t)b * ROW_ + c2 * D2_);
#pragma unroll
      for (int j = 0; j < 8; ++j) va[j] += wp[j];
    }
  }

  v4f acc4[4];
#pragma unroll
  for (int j = 0; j < 4; ++j) acc4[j] = (v4f){0.f, 0.f, 0.f, 0.f};
  v2f* acc = reinterpret_cast<v2f*>(acc4);

  const size_t off = ((size_t)b * C1_ + (size_t)blk * C1B) * ROW_ + (size_t)c2 * D2_;
#pragma unroll 2
  for (int r = rs; r < C1B; r += 8) {
    const v4u* hp = reinterpret_cast<const v4u*>(xb + off + (size_t)r * ROW_);
    const v4u u0 = hp[0], u1 = hp[1];
    const unsigned u[8] = {u0.x, u0.y, u0.z, u0.w, u1.x, u1.y, u1.z, u1.w};
    v2f xv[8];
#pragma unroll
    for (int i = 0; i < 8; ++i) {
      xv[i].x = asf(u[i] << 16);
      xv[i].y = asf(u[i] & 0xffff0000u);
    }
    v2f dp = {0.f, 0.f};
#pragma unroll
    for (int i = 0; i < 8; ++i) pk_fma(dp, xv[i], va[i]);
    const float a = dp.x + dp.y;  // |a| <~ 15 -> exp safe without max-shift
    const float e = __expf(a);
    float s = e;
#pragma unroll
    for (int o = 16; o; o >>= 1) s += __shfl_xor(s, o, 32);
    const float w = e * __builtin_amdgcn_rcpf(s);
    const v2f w2 = {w, w};
#pragma unroll
    for (int i = 0; i < 8; ++i) pk_fma(acc[i], xv[i], w2);
  }

  __shared__ float red[4][ROW_];
  reduce_store(red, reinterpret_cast<float*>(acc4), P, b, blk, tid, c2);
}

// Fold BPB per-block partials, apply scale + bias, squash over D2, write v.
// One thread per (b,c2,d2-quad): 4096 threads; squash norm via 4-lane shfl.
__global__ __launch_bounds__(256) void squash_reduce(
    const float* __restrict__ P, const float* __restrict__ bias,
    float* __restrict__ out, float scale) {
  const int gid = blockIdx.x * 256 + threadIdx.x;
  const int j  = gid & 3;
  const int c2 = (gid >> 2) & 31;
  const int b  = gid >> 7;
  if (b >= B_) return;

  const float* pb = P + (size_t)b * BPB * ROW_ + c2 * D2_ + j * 4;
  v4f s = {0.f, 0.f, 0.f, 0.f};
#pragma unroll 8
  for (int k = 0; k < BPB; ++k)
    s += *reinterpret_cast<const v4f*>(pb + (size_t)k * ROW_);

  const v4f bj = *reinterpret_cast<const v4f*>(bias + c2 * D2_ + j * 4);
  v4f t = s * scale + bj;
  float sq = t.x * t.x + t.y * t.y + t.z * t.z + t.w * t.w;
  sq += __shfl_xor(sq, 1, 4);
  sq += __shfl_xor(sq, 2, 4);
  const float f = sq / ((1.f + sq) * sqrtf(sq + 1e-8f));
  *reinterpret_cast<v4f*>(out + (size_t)b * ROW_ + c2 * D2_ + j * 4) = t * f;
}

// ---------- fp32 fallback (R2 path) if workspace is too small ----------
__global__ __launch_bounds__(256) void fb_pass(
    const float* __restrict__ x, const float* __restrict__ v0,
    const float* __restrict__ v1, float* __restrict__ P, int phase) {
  const int tid = threadIdx.x;
  const int c2 = tid & 31, rs = tid >> 5;
  const int b = blockIdx.x / BPB, blk = blockIdx.x % BPB;
  v2f va[8];
  if (phase >= 1) {
    const v2f* vp = reinterpret_cast<const v2f*>(v0 + (size_t)b * ROW_ + c2 * D2_);
#pragma unroll
    for (int j = 0; j < 8; ++j) va[j] = vp[j];
    if (phase == 2) {
      const v2f* wp = reinterpret_cast<const v2f*>(v1 + (size_t)b * ROW_ + c2 * D2_);
#pragma unroll
      for (int j = 0; j < 8; ++j) va[j] += wp[j];
    }
  }
  v4f acc4[4];
#pragma unroll
  for (int j = 0; j < 4; ++j) acc4[j] = (v4f){0.f, 0.f, 0.f, 0.f};
  v2f* acc = reinterpret_cast<v2f*>(acc4);
  const size_t off = ((size_t)b * C1_ + (size_t)blk * C1B) * ROW_ + (size_t)c2 * D2_;
  for (int r = rs; r < C1B; r += 8) {
    const v4f* xp = reinterpret_cast<const v4f*>(x + off + (size_t)r * ROW_);
    v4f x4[4];
#pragma unroll
    for (int j = 0; j < 4; ++j) x4[j] = xp[j];
    v2f* x2 = reinterpret_cast<v2f*>(x4);
    float w = 1.0f;
    if (phase >= 1) {
      v2f dp = {0.f, 0.f};
#pragma unroll
      for (int j = 0; j < 8; ++j) pk_fma(dp, x2[j], va[j]);
      const float a = dp.x + dp.y;
      const float e = __expf(a);
      float s = e;
#pragma unroll
      for (int o = 16; o; o >>= 1) s += __shfl_xor(s, o, 32);
      w = e * __builtin_amdgcn_rcpf(s);
    }
    const v2f w2 = {w, w};
#pragma unroll
    for (int j = 0; j < 8; ++j) pk_fma(acc[j], x2[j], w2);
  }
  __shared__ float red[4][ROW_];
  reduce_store(red, reinterpret_cast<float*>(acc4), P, b, blk, tid, c2);
}

}  // namespace

extern "C" void kernel_launch(void* const* d_in, const int* in_sizes, int n_in,
                              void* d_out, int out_size, void* d_ws, size_t ws_size,
                              hipStream_t stream) {
  const float* x    = reinterpret_cast<const float*>(d_in[0]);  // digit_caps
  const float* bias = reinterpret_cast<const float*>(d_in[2]);
  float* out = reinterpret_cast<float*>(d_out);

  const size_t xb_elems = (size_t)B_ * C1_ * ROW_;   // 64 Mi bf16 = 128 MiB
  const size_t P_elems  = (size_t)B_ * BPB * ROW_;   // 4 MiB fp32
  const size_t v_elems  = (size_t)B_ * ROW_;         // 64 KiB fp32
  const size_t need = xb_elems * 2 + (P_elems + 2 * v_elems) * 4;

  const dim3 grid(B_ * BPB);
  const dim3 blk(256);
  const dim3 sgrid((B_ * C2_ * 4 + 255) / 256);

  if (ws_size >= need) {
    unsigned short* xb = reinterpret_cast<unsigned short*>(d_ws);
    float* P  = reinterpret_cast<float*>(xb + xb_elems);
    float* v0 = P + P_elems;
    float* v1 = v0 + v_elems;
    pass0<<<grid, blk, 0, stream>>>(x, xb, P);
    squash_reduce<<<sgrid, blk, 0, stream>>>(P, bias, v0, 1.0f / C2_);
    passN<1><<<grid, blk, 0, stream>>>(xb, v0, nullptr, P);
    squash_reduce<<<sgrid, blk, 0, stream>>>(P, bias, v1, 1.0f);
    passN<2><<<grid, blk, 0, stream>>>(xb, v0, v1, P);
    squash_reduce<<<sgrid, blk, 0, stream>>>(P, bias, out, 1.0f);
  } else {
    float* P  = reinterpret_cast<float*>(d_ws);
    float* v0 = P + P_elems;
    float* v1 = v0 + v_elems;
    fb_pass<<<grid, blk, 0, stream>>>(x, nullptr, nullptr, P, 0);
    squash_reduce<<<sgrid, blk, 0, stream>>>(P, bias, v0, 1.0f / C2_);
    fb_pass<<<grid, blk, 0, stream>>>(x, v0, nullptr, P, 1);
    squash_reduce<<<sgrid, blk, 0, stream>>>(P, bias, v1, 1.0f);
    fb_pass<<<grid, blk, 0, stream>>>(x, v0, v1, P, 2);
    squash_reduce<<<sgrid, blk, 0, stream>>>(P, bias, out, 1.0f);
  }
}

// Round 5
// 167.901 us; speedup vs baseline: 5.4801x; 1.0366x over previous
//
#include <hip/hip_runtime.h>
#include <cstddef>

// DynamicRouting: B=32, C1=4096, C2=32, D2=16, 3 routing iterations.
// digit_caps_stopped == digit_caps (bit-identical) -> read d_in[0] only.
//
// iter0: w = 1/32 uniform            -> v0 = squash(colsum(x)/32 + bias)
// iter1: w1 = softmax_c2(x.v0)       -> v1 = squash(sum_c1 w1*x + bias)
// iter2: w2 = softmax_c2(x.(v0+v1))  -> out = squash(sum_c1 w2*x + bias)
//
// Structure (R5): 4 launches, fence-free (R3 lesson: agent-scope fences
// flush non-coherent per-XCD L2s, 10x). Cross-block sync = kernel boundary.
//   pass0: stream fp32 x (nontemporal), colsum partials P0, write bf16 xb
//   pass1: prologue folds P0 -> v0 (redundant per block, 32KB from L2/L3),
//          softmax/accumulate from xb -> P1
//   pass2: prologue folds P0->v0 and P1->v1, main loop -> P2
//   squash_final: fold P2 + bias + squash -> out
// BPB=16 partials/batch keeps the redundant prologue fold cheap; 1024-thread
// blocks keep occupancy at 32 waves/CU with only 512 blocks.

namespace {
typedef float  v2f __attribute__((ext_vector_type(2)));
typedef float  v4f __attribute__((ext_vector_type(4)));
typedef unsigned int v4u __attribute__((ext_vector_type(4)));

constexpr int B_  = 32;
constexpr int C1_ = 4096;
constexpr int C2_ = 32;
constexpr int D2_ = 16;
constexpr int ROW_ = C2_ * D2_;   // 512 elems per (b,c1)
constexpr int BPB  = 16;          // partial blocks per batch element
constexpr int C1B  = C1_ / BPB;   // 256 rows per block
constexpr int TPB  = 1024;        // threads per block (16 waves)

__device__ inline void pk_fma(v2f& c, v2f a, v2f b) {
  asm("v_pk_fma_f32 %0, %1, %2, %0" : "+v"(c) : "v"(a), "v"(b));
}
__device__ inline void pk_add(v2f& c, v2f a) {
  asm("v_pk_add_f32 %0, %1, %0" : "+v"(c) : "v"(a));
}
__device__ inline float asf(unsigned u) { union { unsigned u; float f; } c; c.u = u; return c.f; }
__device__ inline unsigned asu(float f) { union { float f; unsigned u; } c; c.f = f; return c.u; }
__device__ inline unsigned bf16rne(float f) {  // round-to-nearest-even bf16 bits
  unsigned u = asu(f);
  return (u + 0x7fffu + ((u >> 16) & 1u)) >> 16;
}

// Fold BPB partials of one column-quad q (0..127) for batch b, add bias,
// squash over D2 (4-lane shfl), write 4 floats to vout[q*4..]. Deterministic
// (same order every caller) -> redundant per-block copies are bit-identical.
__device__ inline void foldv(const float* __restrict__ P,
                             const float* __restrict__ bias, float scale,
                             int b, int q, float* vout) {
  v4f s = {0.f, 0.f, 0.f, 0.f};
  const float* base = P + (size_t)b * BPB * ROW_ + q * 4;
#pragma unroll 4
  for (int k = 0; k < BPB; ++k)
    s += *reinterpret_cast<const v4f*>(base + (size_t)k * ROW_);
  const v4f bq = *reinterpret_cast<const v4f*>(bias + q * 4);
  v4f t = s * scale + bq;
  float sq = t.x * t.x + t.y * t.y + t.z * t.z + t.w * t.w;
  sq += __shfl_xor(sq, 1, 4);
  sq += __shfl_xor(sq, 2, 4);
  const float f = sq / ((1.f + sq) * sqrtf(sq + 1e-8f));
  *reinterpret_cast<v4f*>(vout + q * 4) = t * f;
}

// PHASE 0: fp32 x (nontemporal), uniform weights, optional bf16 copy out.
// PHASE 1: weights = softmax(x.v0);  PHASE 2: weights = softmax(x.(v0+v1)).
// BF16 selects the xb input path for PHASE>=1.
template <int PHASE, bool BF16, bool WXB>
__global__ __launch_bounds__(TPB) void pass_k(
    const float* __restrict__ x, const unsigned short* __restrict__ xb,
    unsigned short* __restrict__ xbo, const float* __restrict__ bias,
    const float* __restrict__ P0, const float* __restrict__ P1,
    float* __restrict__ Pout) {
  const int tid = threadIdx.x;
  const int c2 = tid & 31, rs = tid >> 5;  // rs in 0..31
  const int b = blockIdx.x / BPB, blk = blockIdx.x % BPB;

  __shared__ alignas(16) float vbuf[2][ROW_];
  __shared__ alignas(16) float red[16][ROW_];

  v2f va[8];
  if (PHASE >= 1) {
    if (tid < 128) {
      foldv(P0, bias, 1.0f / C2_, b, tid, vbuf[0]);         // v0
    } else if (PHASE == 2 && tid < 256) {
      foldv(P1, bias, 1.0f, b, tid - 128, vbuf[1]);         // v1
    }
    __syncthreads();
    const float* v = &vbuf[0][c2 * D2_];
    const float* w = &vbuf[1][c2 * D2_];
#pragma unroll
    for (int j = 0; j < 8; ++j) {
      va[j].x = v[2 * j]     + (PHASE == 2 ? w[2 * j]     : 0.f);
      va[j].y = v[2 * j + 1] + (PHASE == 2 ? w[2 * j + 1] : 0.f);
    }
  }

  v4f acc4[4];
#pragma unroll
  for (int j = 0; j < 4; ++j) acc4[j] = (v4f){0.f, 0.f, 0.f, 0.f};
  v2f* acc = reinterpret_cast<v2f*>(acc4);

  const size_t off =
      ((size_t)b * C1_ + (size_t)blk * C1B) * ROW_ + (size_t)c2 * D2_;
#pragma unroll 2
  for (int r = rs; r < C1B; r += 32) {
    v2f xv[8];
    if (PHASE == 0 || !BF16) {
      const v4f* xp = reinterpret_cast<const v4f*>(x + off + (size_t)r * ROW_);
      v4f x4[4];
#pragma unroll
      for (int j = 0; j < 4; ++j)
        x4[j] = (PHASE == 0) ? __builtin_nontemporal_load(xp + j) : xp[j];
      const v2f* x2 = reinterpret_cast<const v2f*>(x4);
#pragma unroll
      for (int j = 0; j < 8; ++j) xv[j] = x2[j];
      if (PHASE == 0 && WXB) {  // bf16 copy (RNE), 2x16B stores
        const float* xf = reinterpret_cast<const float*>(x4);
        unsigned hw[8];
#pragma unroll
        for (int i = 0; i < 8; ++i)
          hw[i] = bf16rne(xf[2 * i]) | (bf16rne(xf[2 * i + 1]) << 16);
        v4u* hp = reinterpret_cast<v4u*>(xbo + off + (size_t)r * ROW_);
        hp[0] = (v4u){hw[0], hw[1], hw[2], hw[3]};
        hp[1] = (v4u){hw[4], hw[5], hw[6], hw[7]};
      }
    } else {
      const v4u* hp = reinterpret_cast<const v4u*>(xb + off + (size_t)r * ROW_);
      const v4u u0 = hp[0], u1 = hp[1];
      const unsigned u[8] = {u0.x, u0.y, u0.z, u0.w, u1.x, u1.y, u1.z, u1.w};
#pragma unroll
      for (int i = 0; i < 8; ++i) {
        xv[i].x = asf(u[i] << 16);
        xv[i].y = asf(u[i] & 0xffff0000u);
      }
    }

    if (PHASE == 0) {
#pragma unroll
      for (int j = 0; j < 8; ++j) pk_add(acc[j], xv[j]);
    } else {
      v2f dp = {0.f, 0.f};
#pragma unroll
      for (int j = 0; j < 8; ++j) pk_fma(dp, xv[j], va[j]);
      const float a = dp.x + dp.y;  // |a| <~ 15 -> exp safe without max-shift
      const float e = __expf(a);
      float s = e;
#pragma unroll
      for (int o = 16; o; o >>= 1) s += __shfl_xor(s, o, 32);
      const float w = e * __builtin_amdgcn_rcpf(s);
      const v2f w2 = {w, w};
#pragma unroll
      for (int j = 0; j < 8; ++j) pk_fma(acc[j], xv[j], w2);
    }
  }

  // tail: row-slot-pair reduce (lane l <-> l^32), 16 wave-partials via LDS,
  // block partial -> Pout[b][blk][512].
  float* af = reinterpret_cast<float*>(acc4);
#pragma unroll
  for (int k = 0; k < 16; ++k) af[k] += __shfl_xor(af[k], 32);
  const int wave = tid >> 6, lane = tid & 63;
  if (lane < 32) {
    v4f* dst = reinterpret_cast<v4f*>(&red[wave][c2 * D2_]);
    const v4f* s4 = reinterpret_cast<const v4f*>(acc4);
#pragma unroll
    for (int k = 0; k < 4; ++k) { const int jj = (k + c2) & 3; dst[jj] = s4[jj]; }
  }
  __syncthreads();
  if (tid < ROW_ / 4) {
    v4f s = {0.f, 0.f, 0.f, 0.f};
#pragma unroll 4
    for (int w = 0; w < 16; ++w) s += reinterpret_cast<const v4f*>(red[w])[tid];
    reinterpret_cast<v4f*>(Pout + ((size_t)b * BPB + blk) * ROW_)[tid] = s;
  }
}

// Final: fold P2 + bias, squash, write out. One thread per (b, column-quad).
__global__ __launch_bounds__(256) void squash_final(
    const float* __restrict__ P, const float* __restrict__ bias,
    float* __restrict__ out) {
  const int gid = blockIdx.x * 256 + threadIdx.x;  // 4096 = 32 b x 128 q
  const int q = gid & 127, b = gid >> 7;
  if (b >= B_) return;
  foldv(P, bias, 1.0f, b, q, out + (size_t)b * ROW_);
}

}  // namespace

extern "C" void kernel_launch(void* const* d_in, const int* in_sizes, int n_in,
                              void* d_out, int out_size, void* d_ws, size_t ws_size,
                              hipStream_t stream) {
  const float* x    = reinterpret_cast<const float*>(d_in[0]);  // digit_caps
  const float* bias = reinterpret_cast<const float*>(d_in[2]);
  float* out = reinterpret_cast<float*>(d_out);

  const size_t xb_elems = (size_t)B_ * C1_ * ROW_;   // 64 Mi bf16 = 128 MiB
  const size_t P_elems  = (size_t)B_ * BPB * ROW_;   // 1 MiB fp32 each
  const size_t need = xb_elems * 2 + 3 * P_elems * 4;

  const dim3 grid(B_ * BPB);   // 512 blocks
  const dim3 blk(TPB);         // 1024 threads
  const dim3 sgrid(16), sblk(256);

  if (ws_size >= need) {
    unsigned short* xb = reinterpret_cast<unsigned short*>(d_ws);
    float* P0 = reinterpret_cast<float*>(xb + xb_elems);
    float* P1 = P0 + P_elems;
    float* P2 = P1 + P_elems;
    pass_k<0, false, true><<<grid, blk, 0, stream>>>(x, nullptr, xb, bias,
                                                     nullptr, nullptr, P0);
    pass_k<1, true, false><<<grid, blk, 0, stream>>>(x, xb, nullptr, bias,
                                                     P0, nullptr, P1);
    pass_k<2, true, false><<<grid, blk, 0, stream>>>(x, xb, nullptr, bias,
                                                     P0, P1, P2);
    squash_final<<<sgrid, sblk, 0, stream>>>(P2, bias, out);
  } else {
    // fp32 fallback (no bf16 copy); needs only 3 MiB of workspace
    float* P0 = reinterpret_cast<float*>(d_ws);
    float* P1 = P0 + P_elems;
    float* P2 = P1 + P_elems;
    pass_k<0, false, false><<<grid, blk, 0, stream>>>(x, nullptr, nullptr, bias,
                                                      nullptr, nullptr, P0);
    pass_k<1, false, false><<<grid, blk, 0, stream>>>(x, nullptr, nullptr, bias,
                                                      P0, nullptr, P1);
    pass_k<2, false, false><<<grid, blk, 0, stream>>>(x, nullptr, nullptr, bias,
                                                      P0, P1, P2);
    squash_final<<<sgrid, sblk, 0, stream>>>(P2, bias, out);
  }
}